// Round 7
// baseline (756.249 us; speedup 1.0000x reference)
//
#include <hip/hip_runtime.h>

// ---------------- problem constants ----------------
#define T_LEN 2048
#define B_SZ  4
#define D_DIM 2048
#define H_DIM 8192
#define BT    (B_SZ * T_LEN)

typedef float f32x4 __attribute__((ext_vector_type(4)));
typedef int   i32x4v __attribute__((ext_vector_type(4)));
typedef int   i32x16v __attribute__((ext_vector_type(16)));

// ---------------- block reduction (blockDim == 256) ----------------
__device__ __forceinline__ float block_sum(float v, float* red) {
    #pragma unroll
    for (int o = 32; o > 0; o >>= 1) v += __shfl_down(v, o, 64);
    const int lane = threadIdx.x & 63, w = threadIdx.x >> 6;
    if (lane == 0) red[w] = v;
    __syncthreads();
    float r = red[0] + red[1] + red[2] + red[3];
    __syncthreads();
    return r;
}

// ---------------- weight scale: partial abs-sum ----------------
__global__ void wabs_partial(const float* __restrict__ w, int n,
                             float* __restrict__ part) {
    __shared__ float red[16];
    float s = 0.f;
    int i = (blockIdx.x * 256 + threadIdx.x) * 8;
    const int stride = gridDim.x * 256 * 8;
    for (; i < n; i += stride) {
        f32x4 a = *(const f32x4*)(w + i);
        f32x4 b = *(const f32x4*)(w + i + 4);
        #pragma unroll
        for (int j = 0; j < 4; j++) s += fabsf(a[j]) + fabsf(b[j]);
    }
    float tot = block_sum(s, red);
    if (threadIdx.x == 0) part[blockIdx.x] = tot;
}

__global__ void wfinal(const float* __restrict__ part, int nparts, int n,
                       float* __restrict__ outp) {
    __shared__ float red[16];
    float s = 0.f;
    for (int i = threadIdx.x; i < nparts; i += 256) s += part[i];
    float tot = block_sum(s, red);
    if (threadIdx.x == 0) outp[0] = fmaxf(tot / (float)n, 1e-8f);
}

// ---------------- ternary weight quant ----------------
__global__ void wquant(const float* __restrict__ w, const float* __restrict__ sp,
                       signed char* __restrict__ q, int n) {
    const float s = *sp;
    int i = (blockIdx.x * 256 + threadIdx.x) * 16;
    const int stride = gridDim.x * 256 * 16;
    for (; i < n; i += stride) {
        union { signed char c[16]; i32x4v v; } pk;
        #pragma unroll
        for (int h = 0; h < 4; h++) {
            f32x4 a = *(const f32x4*)(w + i + h * 4);
            #pragma unroll
            for (int j = 0; j < 4; j++)
                pk.c[h * 4 + j] =
                    (signed char)(int)rintf(fminf(fmaxf(a[j] / s, -1.f), 1.f));
        }
        *(i32x4v*)(q + i) = pk.v;
    }
}

// ---------------- LN + act quant (8 elems/thread, D=2048) ----------------
__device__ __forceinline__ void ln_quant8(const float* xm_in,
                                          const float* __restrict__ g,
                                          const float* __restrict__ b,
                                          signed char* qrow, float* srow, float* red) {
    const int base = threadIdx.x * 8;
    float xm[8];
    float s = 0.f;
    #pragma unroll
    for (int j = 0; j < 8; j++) { xm[j] = xm_in[j]; s += xm[j]; }
    const float mean = block_sum(s, red) * (1.f / D_DIM);
    float s2 = 0.f;
    #pragma unroll
    for (int j = 0; j < 8; j++) { float d = xm[j] - mean; s2 += d * d; }
    const float var  = block_sum(s2, red) * (1.f / D_DIM);
    const float rstd = 1.f / sqrtf(var + 1e-5f);
    f32x4 ga = *(const f32x4*)(g + base), gb = *(const f32x4*)(g + base + 4);
    f32x4 ba = *(const f32x4*)(b + base), bb2 = *(const f32x4*)(b + base + 4);
    float gg[8] = {ga[0],ga[1],ga[2],ga[3],gb[0],gb[1],gb[2],gb[3]};
    float bb[8] = {ba[0],ba[1],ba[2],ba[3],bb2[0],bb2[1],bb2[2],bb2[3]};
    float sa = 0.f;
    #pragma unroll
    for (int j = 0; j < 8; j++) {
        xm[j] = (xm[j] - mean) * rstd * gg[j] + bb[j];
        sa += fabsf(xm[j]);
    }
    const float amean = block_sum(sa, red) * (1.f / D_DIM);
    const float scale = fmaxf(amean, 1e-8f) * 2.5f / 127.0f;
    union { signed char c[8]; int2 v; } pk;
    #pragma unroll
    for (int j = 0; j < 8; j++)
        pk.c[j] = (signed char)(int)rintf(fminf(fmaxf(xm[j] / scale, -127.f), 127.f));
    *(int2*)(qrow + base) = pk.v;
    if (threadIdx.x == 0) *srow = scale;
}

// ------- token shift + both LN/quant paths + out2 passthrough (f32) -------
__global__ void act_prep(const float* __restrict__ x, int row0,
                         const float* __restrict__ muk,
                         const float* __restrict__ gk, const float* __restrict__ bk,
                         const float* __restrict__ mur,
                         const float* __restrict__ gr, const float* __restrict__ br,
                         signed char* __restrict__ qk, float* __restrict__ sk,
                         signed char* __restrict__ qr, float* __restrict__ sr,
                         float* __restrict__ out2) {
    __shared__ float red[16];
    const int lrow = blockIdx.x;
    const int row = row0 + lrow;
    const int t = row & (T_LEN - 1);
    const int base = threadIdx.x * 8;

    float xv[8], xp[8];
    f32x4 xa = *(const f32x4*)(x + (size_t)row * D_DIM + base);
    f32x4 xb = *(const f32x4*)(x + (size_t)row * D_DIM + base + 4);
    xv[0]=xa[0]; xv[1]=xa[1]; xv[2]=xa[2]; xv[3]=xa[3];
    xv[4]=xb[0]; xv[5]=xb[1]; xv[6]=xb[2]; xv[7]=xb[3];
    if (t > 0) {
        f32x4 pa = *(const f32x4*)(x + (size_t)(row - 1) * D_DIM + base);
        f32x4 pb = *(const f32x4*)(x + (size_t)(row - 1) * D_DIM + base + 4);
        xp[0]=pa[0]; xp[1]=pa[1]; xp[2]=pa[2]; xp[3]=pa[3];
        xp[4]=pb[0]; xp[5]=pb[1]; xp[6]=pb[2]; xp[7]=pb[3];
    } else {
        #pragma unroll
        for (int j = 0; j < 8; j++) xp[j] = 0.f;
    }
    if (t == T_LEN - 1) {
        const int bb = row / T_LEN;
        *(f32x4*)(out2 + (size_t)bb * D_DIM + base)     = xa;   // f32 x[:, -1, :]
        *(f32x4*)(out2 + (size_t)bb * D_DIM + base + 4) = xb;
    }
    float mk[8], mr[8], xmk[8], xmr[8];
    f32x4 mka = *(const f32x4*)(muk + base), mkb = *(const f32x4*)(muk + base + 4);
    f32x4 mra = *(const f32x4*)(mur + base), mrb = *(const f32x4*)(mur + base + 4);
    mk[0]=mka[0]; mk[1]=mka[1]; mk[2]=mka[2]; mk[3]=mka[3];
    mk[4]=mkb[0]; mk[5]=mkb[1]; mk[6]=mkb[2]; mk[7]=mkb[3];
    mr[0]=mra[0]; mr[1]=mra[1]; mr[2]=mra[2]; mr[3]=mra[3];
    mr[4]=mrb[0]; mr[5]=mrb[1]; mr[6]=mrb[2]; mr[7]=mrb[3];
    #pragma unroll
    for (int j = 0; j < 8; j++) {
        const float dx = xp[j] - xv[j];
        xmk[j] = xv[j] + dx * mk[j];
        xmr[j] = xv[j] + dx * mr[j];
    }
    ln_quant8(xmk, gk, bk, qk + (size_t)lrow * D_DIM, sk + lrow, red);
    ln_quant8(xmr, gr, br, qr + (size_t)lrow * D_DIM, sr + lrow, red);
}

// -------- LN + act quant over H=8192 (k_act f32 rows) --------
__global__ void lnq_v(const float* __restrict__ kact,
                      const float* __restrict__ g, const float* __restrict__ b,
                      signed char* __restrict__ qv, float* __restrict__ sv) {
    __shared__ float red[16];
    const int row = blockIdx.x;
    const int base = threadIdx.x * 32;
    const float* kr = kact + (size_t)row * H_DIM + base;

    float v[32];
    float s = 0.f;
    #pragma unroll
    for (int c = 0; c < 8; c++) {
        f32x4 a = *(const f32x4*)(kr + c * 4);
        #pragma unroll
        for (int j = 0; j < 4; j++) { v[c * 4 + j] = a[j]; s += a[j]; }
    }
    const float mean = block_sum(s, red) * (1.f / H_DIM);
    float s2 = 0.f;
    #pragma unroll
    for (int j = 0; j < 32; j++) { float d = v[j] - mean; s2 += d * d; }
    const float var  = block_sum(s2, red) * (1.f / H_DIM);
    const float rstd = 1.f / sqrtf(var + 1e-5f);
    float sa = 0.f;
    #pragma unroll
    for (int c = 0; c < 8; c++) {
        f32x4 ga = *(const f32x4*)(g + base + c * 4);
        f32x4 ba = *(const f32x4*)(b + base + c * 4);
        #pragma unroll
        for (int j = 0; j < 4; j++) {
            int k = c * 4 + j;
            v[k] = (v[k] - mean) * rstd * ga[j] + ba[j];
            sa += fabsf(v[k]);
        }
    }
    const float amean = block_sum(sa, red) * (1.f / H_DIM);
    const float scale = fmaxf(amean, 1e-8f) * 2.5f / 127.0f;
    union { signed char c[32]; i32x4v v4[2]; } pk;
    #pragma unroll
    for (int j = 0; j < 32; j++)
        pk.c[j] = (signed char)(int)rintf(fminf(fmaxf(v[j] / scale, -127.f), 127.f));
    *(i32x4v*)(qv + (size_t)row * H_DIM + base)      = pk.v4[0];
    *(i32x4v*)(qv + (size_t)row * H_DIM + base + 16) = pk.v4[1];
    if (threadIdx.x == 0) sv[row] = scale;
}

// ---------------- i8 MFMA GEMM, double-buffered pipeline ----------------
// C[m,n] = sa[m]*sw * sum_k A[m,k]*B[n,k].  128x128 tile, BK=128 B, 4 waves (2x2),
// each wave 64x64 via 2x2 of 32x32x32 i8 MFMA.  LDS XOR-swizzle on 16B slots
// (linear gload_lds dest + inverse-swizzled global src + swizzled ds_read).
// Pipeline (T3-min + T4 counted vmcnt + T5 setprio): prefetch next K-tile into
// the other LDS buffer, wait vmcnt(8) (prefetch stays in flight across barrier).
// EP: 0 = relu(v)^2 -> f32;  1 = sigmoid(v) -> f32;  2 = out = gate * v (f32).
template <int EP>
__global__ __launch_bounds__(256) void gemm_i8(
    const signed char* __restrict__ A, const signed char* __restrict__ B,
    int K, int Nn,
    const float* __restrict__ sa, const float* __restrict__ swp,
    const float* __restrict__ gate, float* __restrict__ out_f) {
    __shared__ signed char As[2][128 * 128];
    __shared__ signed char Bs[2][128 * 128];
    const int tid  = threadIdx.x;
    const int bm   = blockIdx.x, bn = blockIdx.y;
    const int lane = tid & 63, wave = tid >> 6;
    const int wr = wave >> 1, wc = wave & 1;
    const int lrow = lane & 31, lhalf = lane >> 5;

    i32x16v acc[2][2] = {};

    // staging geometry: 4 x 16B per thread per matrix (linear LDS dest)
    int srow[4], scol[4];
    #pragma unroll
    for (int i = 0; i < 4; i++) {
        int o = i * 256 + tid;
        int r = o >> 3, sl = o & 7;
        srow[i] = r;
        scol[i] = ((sl ^ (r & 7)) * 16);   // inverse-swizzled global source
    }
    const size_t arow0 = (size_t)bm * 128;
    const size_t brow0 = (size_t)bn * 128;
    const int NT = K >> 7;

    auto stage = [&](int buf, int k0) {
        #pragma unroll
        for (int i = 0; i < 4; i++) {
            const signed char* ga = A + (arow0 + srow[i]) * (size_t)K + k0 + scol[i];
            const signed char* gb = B + (brow0 + srow[i]) * (size_t)K + k0 + scol[i];
            __builtin_amdgcn_global_load_lds(
                (const __attribute__((address_space(1))) void*)ga,
                (__attribute__((address_space(3))) void*)(As[buf] + (i * 256 + tid) * 16),
                16, 0, 0);
            __builtin_amdgcn_global_load_lds(
                (const __attribute__((address_space(1))) void*)gb,
                (__attribute__((address_space(3))) void*)(Bs[buf] + (i * 256 + tid) * 16),
                16, 0, 0);
        }
    };

    stage(0, 0);                       // prologue: tile 0 into buf 0
    for (int t = 0; t < NT; t++) {
        const int cur = t & 1;
        if (t + 1 < NT) {
            stage(cur ^ 1, (t + 1) << 7);                    // prefetch next tile
            asm volatile("s_waitcnt vmcnt(8)" ::: "memory"); // tile t's 8 loads done
        } else {
            asm volatile("s_waitcnt vmcnt(0)" ::: "memory"); // final drain
        }
        __builtin_amdgcn_sched_barrier(0);
        __builtin_amdgcn_s_barrier();      // all waves' tile-t LDS writes visible
        __builtin_amdgcn_sched_barrier(0);

        __builtin_amdgcn_s_setprio(1);
        #pragma unroll
        for (int ks = 0; ks < 4; ks++) {
            const int slot = ks * 2 + lhalf;   // 16B slot (global k units)
            i32x4v af[2], bfv[2];
            #pragma unroll
            for (int tm = 0; tm < 2; tm++) {
                int r = wr * 64 + tm * 32 + lrow;
                af[tm] = *(const i32x4v*)(As[cur] + r * 128 + ((slot ^ (r & 7)) * 16));
            }
            #pragma unroll
            for (int tn = 0; tn < 2; tn++) {
                int r = wc * 64 + tn * 32 + lrow;
                bfv[tn] = *(const i32x4v*)(Bs[cur] + r * 128 + ((slot ^ (r & 7)) * 16));
            }
            #pragma unroll
            for (int tm = 0; tm < 2; tm++)
                #pragma unroll
                for (int tn = 0; tn < 2; tn++)
                    acc[tm][tn] = __builtin_amdgcn_mfma_i32_32x32x32_i8(
                        af[tm], bfv[tn], acc[tm][tn], 0, 0, 0);
        }
        __builtin_amdgcn_s_setprio(0);
        __builtin_amdgcn_sched_barrier(0);
        // all waves done reading buf[cur] (their MFMA uses forced lgkm waits)
        // before iteration t+1 overwrites it via stage(cur).
        __builtin_amdgcn_s_barrier();
    }

    const float sw = *swp;
    #pragma unroll
    for (int tm = 0; tm < 2; tm++) {
        #pragma unroll
        for (int tn = 0; tn < 2; tn++) {
            #pragma unroll
            for (int rg = 0; rg < 16; rg++) {
                const int rin  = (rg & 3) + 8 * (rg >> 2) + 4 * lhalf;
                const int grow = bm * 128 + wr * 64 + tm * 32 + rin;
                const int gcol = bn * 128 + wc * 64 + tn * 32 + lrow;
                const float v = (float)acc[tm][tn][rg] * sa[grow] * sw;
                const size_t idx = (size_t)grow * Nn + gcol;
                if (EP == 0) {
                    float rv = fmaxf(v, 0.f);
                    out_f[idx] = rv * rv;
                } else if (EP == 1) {
                    out_f[idx] = 1.0f / (1.0f + expf(-v));
                } else {
                    out_f[idx] = gate[idx] * v;
                }
            }
        }
    }
}

extern "C" void kernel_launch(void* const* d_in, const int* in_sizes, int n_in,
                              void* d_out, int out_size, void* d_ws, size_t ws_size,
                              hipStream_t stream) {
    const float* x   = (const float*)d_in[0];
    const float* muk = (const float*)d_in[1];
    const float* mur = (const float*)d_in[2];
    const float* wk  = (const float*)d_in[3];
    const float* gk  = (const float*)d_in[4];
    const float* bk  = (const float*)d_in[5];
    const float* wr  = (const float*)d_in[6];
    const float* gr  = (const float*)d_in[7];
    const float* br  = (const float*)d_in[8];
    const float* wv  = (const float*)d_in[9];
    const float* gv  = (const float*)d_in[10];
    const float* bv  = (const float*)d_in[11];

    // ---- adaptive workspace layout (pure function of ws_size) ----
    char* wsb = (char*)d_ws;
    size_t off = 0;
    auto alloc = [&](size_t bytes) -> size_t {
        size_t p = off;
        off = (off + bytes + 255) & ~(size_t)255;
        return p;
    };
    const size_t o_wqk  = alloc((size_t)H_DIM * D_DIM);
    const size_t o_wqr  = alloc((size_t)D_DIM * D_DIM);
    const size_t o_wqv  = alloc((size_t)D_DIM * H_DIM);
    const size_t o_wsc  = alloc(64);
    const size_t o_part = alloc(3 * 1024 * sizeof(float));
    const size_t fixed  = off;

    // per-chunk: xqk(CH*D)+xqr(CH*D)+xqv(CH*H)+kact(CH*H*4)+gate(CH*D*4)+scales(3*CH*4)
    int CH = BT;
    while (CH > 128 &&
           fixed + (size_t)CH * (D_DIM + D_DIM + H_DIM + 4 * H_DIM + 4 * D_DIM + 12) + 8192 > ws_size)
        CH >>= 1;
    const size_t o_xqk  = alloc((size_t)CH * D_DIM);
    const size_t o_xqr  = alloc((size_t)CH * D_DIM);
    const size_t o_xqv  = alloc((size_t)CH * H_DIM);
    const size_t o_kact = alloc((size_t)CH * H_DIM * 4);
    const size_t o_gate = alloc((size_t)CH * D_DIM * 4);
    const size_t o_sk   = alloc((size_t)CH * 4);
    const size_t o_sr   = alloc((size_t)CH * 4);
    const size_t o_sv   = alloc((size_t)CH * 4);

    signed char* wqk = (signed char*)(wsb + o_wqk);
    signed char* wqr = (signed char*)(wsb + o_wqr);
    signed char* wqv = (signed char*)(wsb + o_wqv);
    float* wsc  = (float*)(wsb + o_wsc);
    float* part = (float*)(wsb + o_part);
    signed char* xqk = (signed char*)(wsb + o_xqk);
    signed char* xqr = (signed char*)(wsb + o_xqr);
    signed char* xqv = (signed char*)(wsb + o_xqv);
    float* kact = (float*)(wsb + o_kact);
    float* gate = (float*)(wsb + o_gate);
    float* sk = (float*)(wsb + o_sk);
    float* sr = (float*)(wsb + o_sr);
    float* sv = (float*)(wsb + o_sv);

    float* outp = (float*)d_out;                 // f32 output
    float* out2 = outp + (size_t)BT * D_DIM;     // f32 last-token passthrough

    // ---- weight scales + ternary quant ----
    wabs_partial<<<1024, 256, 0, stream>>>(wk, H_DIM * D_DIM, part + 0 * 1024);
    wabs_partial<<<1024, 256, 0, stream>>>(wr, D_DIM * D_DIM, part + 1 * 1024);
    wabs_partial<<<1024, 256, 0, stream>>>(wv, D_DIM * H_DIM, part + 2 * 1024);
    wfinal<<<1, 256, 0, stream>>>(part + 0 * 1024, 1024, H_DIM * D_DIM, wsc + 0);
    wfinal<<<1, 256, 0, stream>>>(part + 1 * 1024, 1024, D_DIM * D_DIM, wsc + 1);
    wfinal<<<1, 256, 0, stream>>>(part + 2 * 1024, 1024, D_DIM * H_DIM, wsc + 2);
    wquant<<<2048, 256, 0, stream>>>(wk, wsc + 0, wqk, H_DIM * D_DIM);
    wquant<<<2048, 256, 0, stream>>>(wr, wsc + 1, wqr, D_DIM * D_DIM);
    wquant<<<2048, 256, 0, stream>>>(wv, wsc + 2, wqv, D_DIM * H_DIM);

    // ---- row-chunked pipeline ----
    for (int row0 = 0; row0 < BT; row0 += CH) {
        act_prep<<<CH, 256, 0, stream>>>(x, row0, muk, gk, bk, mur, gr, br,
                                         xqk, sk, xqr, sr, out2);

        // gate = sigmoid(bitlinear_r)  (f32)
        gemm_i8<1><<<dim3(CH / 128, D_DIM / 128), 256, 0, stream>>>(
            xqr, wqr, D_DIM, D_DIM, sr, wsc + 1, (const float*)nullptr, gate);

        // kact = relu(bitlinear_k)^2  (f32)
        gemm_i8<0><<<dim3(CH / 128, H_DIM / 128), 256, 0, stream>>>(
            xqk, wqk, D_DIM, H_DIM, sk, wsc + 0, (const float*)nullptr, kact);

        lnq_v<<<CH, 256, 0, stream>>>(kact, gv, bv, xqv, sv);

        // out = gate * bitlinear_v  (f32 -> d_out)
        gemm_i8<2><<<dim3(CH / 128, D_DIM / 128), 256, 0, stream>>>(
            xqv, wqv, H_DIM, D_DIM, sv, wsc + 2,
            gate, outp + (size_t)row0 * D_DIM);
    }
}

// Round 9
// 740.455 us; speedup vs baseline: 1.0213x; 1.0213x over previous
//
#include <hip/hip_runtime.h>

// ---------------- problem constants ----------------
#define T_LEN 2048
#define B_SZ  4
#define D_DIM 2048
#define H_DIM 8192
#define BT    (B_SZ * T_LEN)

typedef float f32x4 __attribute__((ext_vector_type(4)));
typedef int   i32x4v __attribute__((ext_vector_type(4)));
typedef int   i32x16v __attribute__((ext_vector_type(16)));

// ---------------- block reduction (blockDim == 256) ----------------
__device__ __forceinline__ float block_sum(float v, float* red) {
    #pragma unroll
    for (int o = 32; o > 0; o >>= 1) v += __shfl_down(v, o, 64);
    const int lane = threadIdx.x & 63, w = threadIdx.x >> 6;
    if (lane == 0) red[w] = v;
    __syncthreads();
    float r = red[0] + red[1] + red[2] + red[3];
    __syncthreads();
    return r;
}

// ---------------- weight scale: partial abs-sum ----------------
__global__ void wabs_partial(const float* __restrict__ w, int n,
                             float* __restrict__ part) {
    __shared__ float red[16];
    float s = 0.f;
    int i = (blockIdx.x * 256 + threadIdx.x) * 8;
    const int stride = gridDim.x * 256 * 8;
    for (; i < n; i += stride) {
        f32x4 a = *(const f32x4*)(w + i);
        f32x4 b = *(const f32x4*)(w + i + 4);
        #pragma unroll
        for (int j = 0; j < 4; j++) s += fabsf(a[j]) + fabsf(b[j]);
    }
    float tot = block_sum(s, red);
    if (threadIdx.x == 0) part[blockIdx.x] = tot;
}

__global__ void wfinal(const float* __restrict__ part, int nparts, int n,
                       float* __restrict__ outp) {
    __shared__ float red[16];
    float s = 0.f;
    for (int i = threadIdx.x; i < nparts; i += 256) s += part[i];
    float tot = block_sum(s, red);
    if (threadIdx.x == 0) outp[0] = fmaxf(tot / (float)n, 1e-8f);
}

// ---------------- ternary weight quant ----------------
__global__ void wquant(const float* __restrict__ w, const float* __restrict__ sp,
                       signed char* __restrict__ q, int n) {
    const float s = *sp;
    int i = (blockIdx.x * 256 + threadIdx.x) * 16;
    const int stride = gridDim.x * 256 * 16;
    for (; i < n; i += stride) {
        union { signed char c[16]; i32x4v v; } pk;
        #pragma unroll
        for (int h = 0; h < 4; h++) {
            f32x4 a = *(const f32x4*)(w + i + h * 4);
            #pragma unroll
            for (int j = 0; j < 4; j++)
                pk.c[h * 4 + j] =
                    (signed char)(int)rintf(fminf(fmaxf(a[j] / s, -1.f), 1.f));
        }
        *(i32x4v*)(q + i) = pk.v;
    }
}

// ---------------- LN + act quant (8 elems/thread, D=2048) ----------------
__device__ __forceinline__ void ln_quant8(const float* xm_in,
                                          const float* __restrict__ g,
                                          const float* __restrict__ b,
                                          signed char* qrow, float* srow, float* red) {
    const int base = threadIdx.x * 8;
    float xm[8];
    float s = 0.f;
    #pragma unroll
    for (int j = 0; j < 8; j++) { xm[j] = xm_in[j]; s += xm[j]; }
    const float mean = block_sum(s, red) * (1.f / D_DIM);
    float s2 = 0.f;
    #pragma unroll
    for (int j = 0; j < 8; j++) { float d = xm[j] - mean; s2 += d * d; }
    const float var  = block_sum(s2, red) * (1.f / D_DIM);
    const float rstd = 1.f / sqrtf(var + 1e-5f);
    f32x4 ga = *(const f32x4*)(g + base), gb = *(const f32x4*)(g + base + 4);
    f32x4 ba = *(const f32x4*)(b + base), bb2 = *(const f32x4*)(b + base + 4);
    float gg[8] = {ga[0],ga[1],ga[2],ga[3],gb[0],gb[1],gb[2],gb[3]};
    float bb[8] = {ba[0],ba[1],ba[2],ba[3],bb2[0],bb2[1],bb2[2],bb2[3]};
    float sa = 0.f;
    #pragma unroll
    for (int j = 0; j < 8; j++) {
        xm[j] = (xm[j] - mean) * rstd * gg[j] + bb[j];
        sa += fabsf(xm[j]);
    }
    const float amean = block_sum(sa, red) * (1.f / D_DIM);
    const float scale = fmaxf(amean, 1e-8f) * 2.5f / 127.0f;
    union { signed char c[8]; int2 v; } pk;
    #pragma unroll
    for (int j = 0; j < 8; j++)
        pk.c[j] = (signed char)(int)rintf(fminf(fmaxf(xm[j] / scale, -127.f), 127.f));
    *(int2*)(qrow + base) = pk.v;
    if (threadIdx.x == 0) *srow = scale;
}

// ------- token shift + both LN/quant paths + out2 passthrough (f32) -------
__global__ void act_prep(const float* __restrict__ x, int row0,
                         const float* __restrict__ muk,
                         const float* __restrict__ gk, const float* __restrict__ bk,
                         const float* __restrict__ mur,
                         const float* __restrict__ gr, const float* __restrict__ br,
                         signed char* __restrict__ qk, float* __restrict__ sk,
                         signed char* __restrict__ qr, float* __restrict__ sr,
                         float* __restrict__ out2) {
    __shared__ float red[16];
    const int lrow = blockIdx.x;
    const int row = row0 + lrow;
    const int t = row & (T_LEN - 1);
    const int base = threadIdx.x * 8;

    float xv[8], xp[8];
    f32x4 xa = *(const f32x4*)(x + (size_t)row * D_DIM + base);
    f32x4 xb = *(const f32x4*)(x + (size_t)row * D_DIM + base + 4);
    xv[0]=xa[0]; xv[1]=xa[1]; xv[2]=xa[2]; xv[3]=xa[3];
    xv[4]=xb[0]; xv[5]=xb[1]; xv[6]=xb[2]; xv[7]=xb[3];
    if (t > 0) {
        f32x4 pa = *(const f32x4*)(x + (size_t)(row - 1) * D_DIM + base);
        f32x4 pb = *(const f32x4*)(x + (size_t)(row - 1) * D_DIM + base + 4);
        xp[0]=pa[0]; xp[1]=pa[1]; xp[2]=pa[2]; xp[3]=pa[3];
        xp[4]=pb[0]; xp[5]=pb[1]; xp[6]=pb[2]; xp[7]=pb[3];
    } else {
        #pragma unroll
        for (int j = 0; j < 8; j++) xp[j] = 0.f;
    }
    if (t == T_LEN - 1) {
        const int bb = row / T_LEN;
        *(f32x4*)(out2 + (size_t)bb * D_DIM + base)     = xa;   // f32 x[:, -1, :]
        *(f32x4*)(out2 + (size_t)bb * D_DIM + base + 4) = xb;
    }
    float mk[8], mr[8], xmk[8], xmr[8];
    f32x4 mka = *(const f32x4*)(muk + base), mkb = *(const f32x4*)(muk + base + 4);
    f32x4 mra = *(const f32x4*)(mur + base), mrb = *(const f32x4*)(mur + base + 4);
    mk[0]=mka[0]; mk[1]=mka[1]; mk[2]=mka[2]; mk[3]=mka[3];
    mk[4]=mkb[0]; mk[5]=mkb[1]; mk[6]=mkb[2]; mk[7]=mkb[3];
    mr[0]=mra[0]; mr[1]=mra[1]; mr[2]=mra[2]; mr[3]=mra[3];
    mr[4]=mrb[0]; mr[5]=mrb[1]; mr[6]=mrb[2]; mr[7]=mrb[3];
    #pragma unroll
    for (int j = 0; j < 8; j++) {
        const float dx = xp[j] - xv[j];
        xmk[j] = xv[j] + dx * mk[j];
        xmr[j] = xv[j] + dx * mr[j];
    }
    ln_quant8(xmk, gk, bk, qk + (size_t)lrow * D_DIM, sk + lrow, red);
    ln_quant8(xmr, gr, br, qr + (size_t)lrow * D_DIM, sr + lrow, red);
}

// -------- LN + act quant over H=8192 (k_act f32 rows) --------
__global__ void lnq_v(const float* __restrict__ kact,
                      const float* __restrict__ g, const float* __restrict__ b,
                      signed char* __restrict__ qv, float* __restrict__ sv) {
    __shared__ float red[16];
    const int row = blockIdx.x;
    const int base = threadIdx.x * 32;
    const float* kr = kact + (size_t)row * H_DIM + base;

    float v[32];
    float s = 0.f;
    #pragma unroll
    for (int c = 0; c < 8; c++) {
        f32x4 a = *(const f32x4*)(kr + c * 4);
        #pragma unroll
        for (int j = 0; j < 4; j++) { v[c * 4 + j] = a[j]; s += a[j]; }
    }
    const float mean = block_sum(s, red) * (1.f / H_DIM);
    float s2 = 0.f;
    #pragma unroll
    for (int j = 0; j < 32; j++) { float d = v[j] - mean; s2 += d * d; }
    const float var  = block_sum(s2, red) * (1.f / H_DIM);
    const float rstd = 1.f / sqrtf(var + 1e-5f);
    float sa = 0.f;
    #pragma unroll
    for (int c = 0; c < 8; c++) {
        f32x4 ga = *(const f32x4*)(g + base + c * 4);
        f32x4 ba = *(const f32x4*)(b + base + c * 4);
        #pragma unroll
        for (int j = 0; j < 4; j++) {
            int k = c * 4 + j;
            v[k] = (v[k] - mean) * rstd * ga[j] + ba[j];
            sa += fabsf(v[k]);
        }
    }
    const float amean = block_sum(sa, red) * (1.f / H_DIM);
    const float scale = fmaxf(amean, 1e-8f) * 2.5f / 127.0f;
    union { signed char c[32]; i32x4v v4[2]; } pk;
    #pragma unroll
    for (int j = 0; j < 32; j++)
        pk.c[j] = (signed char)(int)rintf(fminf(fmaxf(v[j] / scale, -127.f), 127.f));
    *(i32x4v*)(qv + (size_t)row * H_DIM + base)      = pk.v4[0];
    *(i32x4v*)(qv + (size_t)row * H_DIM + base + 16) = pk.v4[1];
    if (threadIdx.x == 0) sv[row] = scale;
}

// ---------------- i8 MFMA GEMM, 256-row tile, phase-interleaved schedule ----------------
// C[m,n] = sa[m]*sw * sum_k A[m,k]*B[n,k].   BM x BN tile, BK=128 B, 8 waves (WM x WN),
// per-wave (BM/WM) x (BN/WN) via MT x NTC of 32x32x32 i8 MFMA tiles.
// Per K-tile: 2 phases, each = { ds_read 2 k-slices || stage half of next tile
//   -> barrier -> setprio(1) MFMA cluster setprio(0) -> barrier }.
// One counted vmcnt per K-tile (phase 0), never 0 in steady state (T4).
// Staging: ALOADS = BM*128 / (512 thr * 16 B) = BM/64  (r8 bug: was BM/128 -> half-staged).
// LDS XOR-swizzle on 16B slots (linear gload_lds dest + inverse-swizzled global src
// + swizzled ds_read) -- per-lane mapping identical to the numerically-verified core.
// EP: 0 = relu(v)^2 -> f32;  1 = sigmoid(v) -> f32;  2 = out = gate * v (f32).
template <int EP, int BM, int BN, int WM, int WN>
__global__ __launch_bounds__(512, 2) void gemm8(
    const signed char* __restrict__ A, const signed char* __restrict__ B,
    int K, int Nn, int gn,
    const float* __restrict__ sa, const float* __restrict__ swp,
    const float* __restrict__ gate, float* __restrict__ out_f) {
    constexpr int MT  = BM / WM / 32;       // row tiles per wave
    constexpr int NTC = BN / WN / 32;       // col tiles per wave
    constexpr int ALOADS = BM / 64;         // 16B gload_lds per thread per K-tile (A)
    constexpr int BLOADS = BN / 64;
    constexpr int LOADS  = ALOADS + BLOADS;
    constexpr int L0 = LOADS / 2;           // issued in phase 0

    __shared__ signed char As[2][BM * 128];
    __shared__ signed char Bs[2][BN * 128];

    const int tid = threadIdx.x;
    // bijective XCD swizzle (nwg % 8 == 0 guaranteed by host grids)
    const int nwg = gridDim.x;
    const int q8  = nwg >> 3;
    const int swz = (blockIdx.x & 7) * q8 + (blockIdx.x >> 3);
    const int bm = swz / gn, bn = swz % gn;

    const int lane = tid & 63, wave = tid >> 6;
    const int wr = wave / WN, wc = wave % WN;
    const int lrow = lane & 31, lhalf = lane >> 5;

    i32x16v acc[MT][NTC] = {};

    const size_t arow0 = (size_t)bm * BM;
    const size_t brow0 = (size_t)bn * BN;
    const int NT = K >> 7;

    auto stage_one = [&](int buf, int k0, int j) {
        if (j < ALOADS) {
            const int o = j * 512 + tid;
            const int r = o >> 3, sl = o & 7;
            const signed char* g = A + (arow0 + r) * (size_t)K + k0 + ((sl ^ (r & 7)) * 16);
            __builtin_amdgcn_global_load_lds(
                (const __attribute__((address_space(1))) void*)g,
                (__attribute__((address_space(3))) void*)(As[buf] + o * 16), 16, 0, 0);
        } else {
            const int o = (j - ALOADS) * 512 + tid;
            const int r = o >> 3, sl = o & 7;
            const signed char* g = B + (brow0 + r) * (size_t)K + k0 + ((sl ^ (r & 7)) * 16);
            __builtin_amdgcn_global_load_lds(
                (const __attribute__((address_space(1))) void*)g,
                (__attribute__((address_space(3))) void*)(Bs[buf] + o * 16), 16, 0, 0);
        }
    };

    auto read_frags = [&](const signed char* AsB, const signed char* BsB, int ks0,
                          i32x4v (&af)[MT][2], i32x4v (&bf)[NTC][2]) {
        #pragma unroll
        for (int s = 0; s < 2; s++) {
            const int slot = (ks0 + s) * 2 + lhalf;
            #pragma unroll
            for (int tm = 0; tm < MT; tm++) {
                const int r = wr * (MT * 32) + tm * 32 + lrow;
                af[tm][s] = *(const i32x4v*)(AsB + r * 128 + ((slot ^ (r & 7)) * 16));
            }
            #pragma unroll
            for (int tn = 0; tn < NTC; tn++) {
                const int r = wc * (NTC * 32) + tn * 32 + lrow;
                bf[tn][s] = *(const i32x4v*)(BsB + r * 128 + ((slot ^ (r & 7)) * 16));
            }
        }
    };

    auto do_mfma = [&](i32x4v (&af)[MT][2], i32x4v (&bf)[NTC][2]) {
        #pragma unroll
        for (int s = 0; s < 2; s++)
            #pragma unroll
            for (int tm = 0; tm < MT; tm++)
                #pragma unroll
                for (int tn = 0; tn < NTC; tn++)
                    acc[tm][tn] = __builtin_amdgcn_mfma_i32_32x32x32_i8(
                        af[tm][s], bf[tn][s], acc[tm][tn], 0, 0, 0);
    };

    // prologue: tile 0 fully staged into buf 0
    #pragma unroll
    for (int j = 0; j < LOADS; j++) stage_one(0, 0, j);

    for (int t = 0; t < NT; t++) {
        const int cur = t & 1;
        const signed char* AsB = As[cur];
        const signed char* BsB = Bs[cur];
        const int kn = (t + 1) << 7;
        const bool pf = (t + 1 < NT);

        // ---- phase 0 ----
        if (pf) {
            #pragma unroll
            for (int j = 0; j < L0; j++) stage_one(cur ^ 1, kn, j);
            if constexpr (L0 == 4) asm volatile("s_waitcnt vmcnt(4)" ::: "memory");
            else                   asm volatile("s_waitcnt vmcnt(3)" ::: "memory");
        } else {
            asm volatile("s_waitcnt vmcnt(0)" ::: "memory");
        }
        __builtin_amdgcn_sched_barrier(0);
        __builtin_amdgcn_s_barrier();          // tile-t LDS data visible to all waves
        __builtin_amdgcn_sched_barrier(0);
        {
            i32x4v af[MT][2], bf[NTC][2];
            read_frags(AsB, BsB, 0, af, bf);
            __builtin_amdgcn_s_setprio(1);
            do_mfma(af, bf);
            __builtin_amdgcn_s_setprio(0);
        }
        __builtin_amdgcn_sched_barrier(0);
        __builtin_amdgcn_s_barrier();
        // ---- phase 1 ----
        {
            i32x4v af[MT][2], bf[NTC][2];
            read_frags(AsB, BsB, 2, af, bf);   // slices 2-3 (data valid since phase-0 barrier)
            if (pf) {
                #pragma unroll
                for (int j = L0; j < LOADS; j++) stage_one(cur ^ 1, kn, j);
            }
            __builtin_amdgcn_sched_barrier(0);
            __builtin_amdgcn_s_barrier();
            __builtin_amdgcn_sched_barrier(0);
            __builtin_amdgcn_s_setprio(1);
            do_mfma(af, bf);
            __builtin_amdgcn_s_setprio(0);
        }
        __builtin_amdgcn_sched_barrier(0);
        __builtin_amdgcn_s_barrier();          // tile boundary: buf[cur] free for overwrite
    }

    const float sw = *swp;
    #pragma unroll
    for (int tm = 0; tm < MT; tm++) {
        #pragma unroll
        for (int tn = 0; tn < NTC; tn++) {
            #pragma unroll
            for (int rg = 0; rg < 16; rg++) {
                const int rin  = (rg & 3) + 8 * (rg >> 2) + 4 * lhalf;
                const int grow = bm * BM + wr * (MT * 32) + tm * 32 + rin;
                const int gcol = bn * BN + wc * (NTC * 32) + tn * 32 + lrow;
                const float v = (float)acc[tm][tn][rg] * sa[grow] * sw;
                const size_t idx = (size_t)grow * Nn + gcol;
                if (EP == 0) {
                    float rv = fmaxf(v, 0.f);
                    out_f[idx] = rv * rv;
                } else if (EP == 1) {
                    out_f[idx] = 1.0f / (1.0f + expf(-v));
                } else {
                    out_f[idx] = gate[idx] * v;
                }
            }
        }
    }
}

extern "C" void kernel_launch(void* const* d_in, const int* in_sizes, int n_in,
                              void* d_out, int out_size, void* d_ws, size_t ws_size,
                              hipStream_t stream) {
    const float* x   = (const float*)d_in[0];
    const float* muk = (const float*)d_in[1];
    const float* mur = (const float*)d_in[2];
    const float* wk  = (const float*)d_in[3];
    const float* gk  = (const float*)d_in[4];
    const float* bk  = (const float*)d_in[5];
    const float* wr  = (const float*)d_in[6];
    const float* gr  = (const float*)d_in[7];
    const float* br  = (const float*)d_in[8];
    const float* wv  = (const float*)d_in[9];
    const float* gv  = (const float*)d_in[10];
    const float* bv  = (const float*)d_in[11];

    // ---- adaptive workspace layout (pure function of ws_size) ----
    char* wsb = (char*)d_ws;
    size_t off = 0;
    auto alloc = [&](size_t bytes) -> size_t {
        size_t p = off;
        off = (off + bytes + 255) & ~(size_t)255;
        return p;
    };
    const size_t o_wqk  = alloc((size_t)H_DIM * D_DIM);
    const size_t o_wqr  = alloc((size_t)D_DIM * D_DIM);
    const size_t o_wqv  = alloc((size_t)D_DIM * H_DIM);
    const size_t o_wsc  = alloc(64);
    const size_t o_part = alloc(3 * 1024 * sizeof(float));
    const size_t fixed  = off;

    // per-chunk: xqk(CH*D)+xqr(CH*D)+xqv(CH*H)+kact(CH*H*4)+gate(CH*D*4)+scales(3*CH*4)
    int CH = BT;
    while (CH > 256 &&
           fixed + (size_t)CH * (D_DIM + D_DIM + H_DIM + 4 * H_DIM + 4 * D_DIM + 12) + 8192 > ws_size)
        CH >>= 1;
    const size_t o_xqk  = alloc((size_t)CH * D_DIM);
    const size_t o_xqr  = alloc((size_t)CH * D_DIM);
    const size_t o_xqv  = alloc((size_t)CH * H_DIM);
    const size_t o_kact = alloc((size_t)CH * H_DIM * 4);
    const size_t o_gate = alloc((size_t)CH * D_DIM * 4);
    const size_t o_sk   = alloc((size_t)CH * 4);
    const size_t o_sr   = alloc((size_t)CH * 4);
    const size_t o_sv   = alloc((size_t)CH * 4);

    signed char* wqk = (signed char*)(wsb + o_wqk);
    signed char* wqr = (signed char*)(wsb + o_wqr);
    signed char* wqv = (signed char*)(wsb + o_wqv);
    float* wsc  = (float*)(wsb + o_wsc);
    float* part = (float*)(wsb + o_part);
    signed char* xqk = (signed char*)(wsb + o_xqk);
    signed char* xqr = (signed char*)(wsb + o_xqr);
    signed char* xqv = (signed char*)(wsb + o_xqv);
    float* kact = (float*)(wsb + o_kact);
    float* gate = (float*)(wsb + o_gate);
    float* sk = (float*)(wsb + o_sk);
    float* sr = (float*)(wsb + o_sr);
    float* sv = (float*)(wsb + o_sv);

    float* outp = (float*)d_out;                 // f32 output
    float* out2 = outp + (size_t)BT * D_DIM;     // f32 last-token passthrough

    // ---- weight scales + ternary quant ----
    wabs_partial<<<1024, 256, 0, stream>>>(wk, H_DIM * D_DIM, part + 0 * 1024);
    wabs_partial<<<1024, 256, 0, stream>>>(wr, D_DIM * D_DIM, part + 1 * 1024);
    wabs_partial<<<1024, 256, 0, stream>>>(wv, D_DIM * H_DIM, part + 2 * 1024);
    wfinal<<<1, 256, 0, stream>>>(part + 0 * 1024, 1024, H_DIM * D_DIM, wsc + 0);
    wfinal<<<1, 256, 0, stream>>>(part + 1 * 1024, 1024, D_DIM * D_DIM, wsc + 1);
    wfinal<<<1, 256, 0, stream>>>(part + 2 * 1024, 1024, D_DIM * H_DIM, wsc + 2);
    wquant<<<2048, 256, 0, stream>>>(wk, wsc + 0, wqk, H_DIM * D_DIM);
    wquant<<<2048, 256, 0, stream>>>(wr, wsc + 1, wqr, D_DIM * D_DIM);
    wquant<<<2048, 256, 0, stream>>>(wv, wsc + 2, wqv, D_DIM * H_DIM);

    // ---- row-chunked pipeline ----
    for (int row0 = 0; row0 < BT; row0 += CH) {
        act_prep<<<CH, 256, 0, stream>>>(x, row0, muk, gk, bk, mur, gr, br,
                                         xqk, sk, xqr, sr, out2);

        // gate = sigmoid(bitlinear_r)  (f32)   [256x128 tile, 4x2 waves]
        gemm8<1, 256, 128, 4, 2><<<(CH / 256) * (D_DIM / 128), 512, 0, stream>>>(
            xqr, wqr, D_DIM, D_DIM, D_DIM / 128, sr, wsc + 1,
            (const float*)nullptr, gate);

        // kact = relu(bitlinear_k)^2  (f32)    [256x256 tile, 2x4 waves]
        gemm8<0, 256, 256, 2, 4><<<(CH / 256) * (H_DIM / 256), 512, 0, stream>>>(
            xqk, wqk, D_DIM, H_DIM, H_DIM / 256, sk, wsc + 0,
            (const float*)nullptr, kact);

        lnq_v<<<CH, 256, 0, stream>>>(kact, gv, bv, xqv, sv);

        // out = gate * bitlinear_v  (f32 -> d_out)   [256x128 tile, 4x2 waves]
        gemm8<2, 256, 128, 4, 2><<<(CH / 256) * (D_DIM / 128), 512, 0, stream>>>(
            xqv, wqv, H_DIM, D_DIM, D_DIM / 128, sv, wsc + 2,
            gate, outp + (size_t)row0 * D_DIM);
    }
}

// Round 10
// 692.309 us; speedup vs baseline: 1.0924x; 1.0695x over previous
//
#include <hip/hip_runtime.h>

// ---------------- problem constants ----------------
#define T_LEN 2048
#define B_SZ  4
#define D_DIM 2048
#define H_DIM 8192
#define BT    (B_SZ * T_LEN)

typedef float f32x4 __attribute__((ext_vector_type(4)));
typedef int   i32x4v __attribute__((ext_vector_type(4)));
typedef int   i32x16v __attribute__((ext_vector_type(16)));
typedef unsigned short ushort8 __attribute__((ext_vector_type(8)));

__device__ __forceinline__ float bf2f(unsigned short u) {
    unsigned int i = ((unsigned int)u) << 16;
    return __builtin_bit_cast(float, i);
}
__device__ __forceinline__ unsigned short f2bf(float f) {
    unsigned int i = __builtin_bit_cast(unsigned int, f);
    i += 0x7fffu + ((i >> 16) & 1u);   // RNE
    return (unsigned short)(i >> 16);
}

// ---------------- block reduction (blockDim == 256) ----------------
__device__ __forceinline__ float block_sum(float v, float* red) {
    #pragma unroll
    for (int o = 32; o > 0; o >>= 1) v += __shfl_down(v, o, 64);
    const int lane = threadIdx.x & 63, w = threadIdx.x >> 6;
    if (lane == 0) red[w] = v;
    __syncthreads();
    float r = red[0] + red[1] + red[2] + red[3];
    __syncthreads();
    return r;
}

// ---------------- weight scale: partial abs-sum ----------------
__global__ void wabs_partial(const float* __restrict__ w, int n,
                             float* __restrict__ part) {
    __shared__ float red[16];
    float s = 0.f;
    int i = (blockIdx.x * 256 + threadIdx.x) * 8;
    const int stride = gridDim.x * 256 * 8;
    for (; i < n; i += stride) {
        f32x4 a = *(const f32x4*)(w + i);
        f32x4 b = *(const f32x4*)(w + i + 4);
        #pragma unroll
        for (int j = 0; j < 4; j++) s += fabsf(a[j]) + fabsf(b[j]);
    }
    float tot = block_sum(s, red);
    if (threadIdx.x == 0) part[blockIdx.x] = tot;
}

__global__ void wfinal(const float* __restrict__ part, int nparts, int n,
                       float* __restrict__ outp) {
    __shared__ float red[16];
    float s = 0.f;
    for (int i = threadIdx.x; i < nparts; i += 256) s += part[i];
    float tot = block_sum(s, red);
    if (threadIdx.x == 0) outp[0] = fmaxf(tot / (float)n, 1e-8f);
}

// ---------------- ternary weight quant ----------------
__global__ void wquant(const float* __restrict__ w, const float* __restrict__ sp,
                       signed char* __restrict__ q, int n) {
    const float s = *sp;
    int i = (blockIdx.x * 256 + threadIdx.x) * 16;
    const int stride = gridDim.x * 256 * 16;
    for (; i < n; i += stride) {
        union { signed char c[16]; i32x4v v; } pk;
        #pragma unroll
        for (int h = 0; h < 4; h++) {
            f32x4 a = *(const f32x4*)(w + i + h * 4);
            #pragma unroll
            for (int j = 0; j < 4; j++)
                pk.c[h * 4 + j] =
                    (signed char)(int)rintf(fminf(fmaxf(a[j] / s, -1.f), 1.f));
        }
        *(i32x4v*)(q + i) = pk.v;
    }
}

// ---------------- LN + act quant (8 elems/thread, D=2048) ----------------
__device__ __forceinline__ void ln_quant8(const float* xm_in,
                                          const float* __restrict__ g,
                                          const float* __restrict__ b,
                                          signed char* qrow, float* srow, float* red) {
    const int base = threadIdx.x * 8;
    float xm[8];
    float s = 0.f;
    #pragma unroll
    for (int j = 0; j < 8; j++) { xm[j] = xm_in[j]; s += xm[j]; }
    const float mean = block_sum(s, red) * (1.f / D_DIM);
    float s2 = 0.f;
    #pragma unroll
    for (int j = 0; j < 8; j++) { float d = xm[j] - mean; s2 += d * d; }
    const float var  = block_sum(s2, red) * (1.f / D_DIM);
    const float rstd = 1.f / sqrtf(var + 1e-5f);
    f32x4 ga = *(const f32x4*)(g + base), gb = *(const f32x4*)(g + base + 4);
    f32x4 ba = *(const f32x4*)(b + base), bb2 = *(const f32x4*)(b + base + 4);
    float gg[8] = {ga[0],ga[1],ga[2],ga[3],gb[0],gb[1],gb[2],gb[3]};
    float bb[8] = {ba[0],ba[1],ba[2],ba[3],bb2[0],bb2[1],bb2[2],bb2[3]};
    float sa = 0.f;
    #pragma unroll
    for (int j = 0; j < 8; j++) {
        xm[j] = (xm[j] - mean) * rstd * gg[j] + bb[j];
        sa += fabsf(xm[j]);
    }
    const float amean = block_sum(sa, red) * (1.f / D_DIM);
    const float scale = fmaxf(amean, 1e-8f) * 2.5f / 127.0f;
    union { signed char c[8]; int2 v; } pk;
    #pragma unroll
    for (int j = 0; j < 8; j++)
        pk.c[j] = (signed char)(int)rintf(fminf(fmaxf(xm[j] / scale, -127.f), 127.f));
    *(int2*)(qrow + base) = pk.v;
    if (threadIdx.x == 0) *srow = scale;
}

// ------- token shift + both LN/quant paths + out2 passthrough (f32) -------
__global__ void act_prep(const float* __restrict__ x, int row0,
                         const float* __restrict__ muk,
                         const float* __restrict__ gk, const float* __restrict__ bk,
                         const float* __restrict__ mur,
                         const float* __restrict__ gr, const float* __restrict__ br,
                         signed char* __restrict__ qk, float* __restrict__ sk,
                         signed char* __restrict__ qr, float* __restrict__ sr,
                         float* __restrict__ out2) {
    __shared__ float red[16];
    const int lrow = blockIdx.x;
    const int row = row0 + lrow;
    const int t = row & (T_LEN - 1);
    const int base = threadIdx.x * 8;

    float xv[8], xp[8];
    f32x4 xa = *(const f32x4*)(x + (size_t)row * D_DIM + base);
    f32x4 xb = *(const f32x4*)(x + (size_t)row * D_DIM + base + 4);
    xv[0]=xa[0]; xv[1]=xa[1]; xv[2]=xa[2]; xv[3]=xa[3];
    xv[4]=xb[0]; xv[5]=xb[1]; xv[6]=xb[2]; xv[7]=xb[3];
    if (t > 0) {
        f32x4 pa = *(const f32x4*)(x + (size_t)(row - 1) * D_DIM + base);
        f32x4 pb = *(const f32x4*)(x + (size_t)(row - 1) * D_DIM + base + 4);
        xp[0]=pa[0]; xp[1]=pa[1]; xp[2]=pa[2]; xp[3]=pa[3];
        xp[4]=pb[0]; xp[5]=pb[1]; xp[6]=pb[2]; xp[7]=pb[3];
    } else {
        #pragma unroll
        for (int j = 0; j < 8; j++) xp[j] = 0.f;
    }
    if (t == T_LEN - 1) {
        const int bb = row / T_LEN;
        *(f32x4*)(out2 + (size_t)bb * D_DIM + base)     = xa;   // f32 x[:, -1, :]
        *(f32x4*)(out2 + (size_t)bb * D_DIM + base + 4) = xb;
    }
    float mk[8], mr[8], xmk[8], xmr[8];
    f32x4 mka = *(const f32x4*)(muk + base), mkb = *(const f32x4*)(muk + base + 4);
    f32x4 mra = *(const f32x4*)(mur + base), mrb = *(const f32x4*)(mur + base + 4);
    mk[0]=mka[0]; mk[1]=mka[1]; mk[2]=mka[2]; mk[3]=mka[3];
    mk[4]=mkb[0]; mk[5]=mkb[1]; mk[6]=mkb[2]; mk[7]=mkb[3];
    mr[0]=mra[0]; mr[1]=mra[1]; mr[2]=mra[2]; mr[3]=mra[3];
    mr[4]=mrb[0]; mr[5]=mrb[1]; mr[6]=mrb[2]; mr[7]=mrb[3];
    #pragma unroll
    for (int j = 0; j < 8; j++) {
        const float dx = xp[j] - xv[j];
        xmk[j] = xv[j] + dx * mk[j];
        xmr[j] = xv[j] + dx * mr[j];
    }
    ln_quant8(xmk, gk, bk, qk + (size_t)lrow * D_DIM, sk + lrow, red);
    ln_quant8(xmr, gr, br, qr + (size_t)lrow * D_DIM, sr + lrow, red);
}

// -------- LN + act quant over H=8192 (k_act bf16 rows) --------
__global__ void lnq_v(const unsigned short* __restrict__ kact,
                      const float* __restrict__ g, const float* __restrict__ b,
                      signed char* __restrict__ qv, float* __restrict__ sv) {
    __shared__ float red[16];
    const int row = blockIdx.x;
    const int base = threadIdx.x * 32;
    const unsigned short* kr = kact + (size_t)row * H_DIM + base;

    float v[32];
    float s = 0.f;
    #pragma unroll
    for (int c = 0; c < 4; c++) {
        ushort8 a = *(const ushort8*)(kr + c * 8);
        #pragma unroll
        for (int j = 0; j < 8; j++) { v[c * 8 + j] = bf2f(a[j]); s += v[c * 8 + j]; }
    }
    const float mean = block_sum(s, red) * (1.f / H_DIM);
    float s2 = 0.f;
    #pragma unroll
    for (int j = 0; j < 32; j++) { float d = v[j] - mean; s2 += d * d; }
    const float var  = block_sum(s2, red) * (1.f / H_DIM);
    const float rstd = 1.f / sqrtf(var + 1e-5f);
    float sa = 0.f;
    #pragma unroll
    for (int c = 0; c < 8; c++) {
        f32x4 ga = *(const f32x4*)(g + base + c * 4);
        f32x4 ba = *(const f32x4*)(b + base + c * 4);
        #pragma unroll
        for (int j = 0; j < 4; j++) {
            int k = c * 4 + j;
            v[k] = (v[k] - mean) * rstd * ga[j] + ba[j];
            sa += fabsf(v[k]);
        }
    }
    const float amean = block_sum(sa, red) * (1.f / H_DIM);
    const float scale = fmaxf(amean, 1e-8f) * 2.5f / 127.0f;
    union { signed char c[32]; i32x4v v4[2]; } pk;
    #pragma unroll
    for (int j = 0; j < 32; j++)
        pk.c[j] = (signed char)(int)rintf(fminf(fmaxf(v[j] / scale, -127.f), 127.f));
    *(i32x4v*)(qv + (size_t)row * H_DIM + base)      = pk.v4[0];
    *(i32x4v*)(qv + (size_t)row * H_DIM + base + 16) = pk.v4[1];
    if (threadIdx.x == 0) sv[row] = scale;
}

// ---------------- i8 MFMA GEMM, tile/BK-parameterized pipeline ----------------
// C[m,n] = sa[m]*sw * sum_k A[m,k]*B[n,k].  BM x BN tile, BK bytes K-step, 8 waves
// (WM x WN), per-wave MT x NTC of 32x32x32 i8 MFMA.
// BK=128: 2 phases/K-tile (verified r9 path, swizzle f(r)=r&7 on 8 slots).
// BK=64:  1 phase/K-tile  (staging-lean gemm0 path, swizzle f(r)=(r>>1)&3 on 4 slots;
//         same involution structure: linear gload_lds dest + inverse-swz global src
//         + swz ds_read; preserves 8 bank-groups -> 4-way max conflict).
// Counted vmcnt (never 0 mid-loop): WAITN = loads issued before the wait, leaving
// exactly the previous tile's loads to drain.
// EP: 0 = relu(v)^2 -> bf16;  1 = sigmoid(v) -> f32;  2 = out = gate * v (f32).
template <int EP, int BM, int BN, int WM, int WN, int BK>
__global__ __launch_bounds__(512, 2) void gemm8(
    const signed char* __restrict__ A, const signed char* __restrict__ B,
    int K, int Nn, int gn,
    const float* __restrict__ sa, const float* __restrict__ swp,
    const float* __restrict__ gate, float* __restrict__ out_f,
    unsigned short* __restrict__ out_bf) {
    constexpr int MT  = BM / WM / 32;
    constexpr int NTC = BN / WN / 32;
    constexpr int SLOTS  = BK / 16;          // 16B slots per row
    constexpr int ALOADS = BM * BK / 8192;   // 512 thr x 16 B per pass
    constexpr int BLOADS = BN * BK / 8192;
    constexpr int LOADS  = ALOADS + BLOADS;
    constexpr int WAITN  = (BK == 64) ? LOADS : LOADS / 2;

    __shared__ signed char As[2][BM * BK];
    __shared__ signed char Bs[2][BN * BK];

    const int tid = threadIdx.x;
    const int nwg = gridDim.x;               // divisible by 8 (host guarantees)
    const int q8  = nwg >> 3;
    const int swz = (blockIdx.x & 7) * q8 + (blockIdx.x >> 3);
    const int bm = swz / gn, bn = swz % gn;

    const int lane = tid & 63, wave = tid >> 6;
    const int wr = wave / WN, wc = wave % WN;
    const int lrow = lane & 31, lhalf = lane >> 5;

    i32x16v acc[MT][NTC] = {};

    const size_t arow0 = (size_t)bm * BM;
    const size_t brow0 = (size_t)bn * BN;
    const int NT = K / BK;

    auto fswz = [&](int r) -> int {
        if constexpr (BK == 128) return r & 7;
        else                     return (r >> 1) & 3;
    };

    auto stage_one = [&](int buf, int k0, int j) {
        if (j < ALOADS) {
            const int o = j * 512 + tid;
            const int r = o / SLOTS, sl = o % SLOTS;
            const signed char* g = A + (arow0 + r) * (size_t)K + k0 + ((sl ^ fswz(r)) * 16);
            __builtin_amdgcn_global_load_lds(
                (const __attribute__((address_space(1))) void*)g,
                (__attribute__((address_space(3))) void*)(As[buf] + o * 16), 16, 0, 0);
        } else {
            const int o = (j - ALOADS) * 512 + tid;
            const int r = o / SLOTS, sl = o % SLOTS;
            const signed char* g = B + (brow0 + r) * (size_t)K + k0 + ((sl ^ fswz(r)) * 16);
            __builtin_amdgcn_global_load_lds(
                (const __attribute__((address_space(1))) void*)g,
                (__attribute__((address_space(3))) void*)(Bs[buf] + o * 16), 16, 0, 0);
        }
    };

    auto read_slice = [&](const signed char* AsB, const signed char* BsB, int s,
                          i32x4v (&af)[MT], i32x4v (&bf)[NTC]) {
        const int slot = s * 2 + lhalf;
        #pragma unroll
        for (int tm = 0; tm < MT; tm++) {
            const int r = wr * (MT * 32) + tm * 32 + lrow;
            af[tm] = *(const i32x4v*)(AsB + r * BK + ((slot ^ fswz(r)) * 16));
        }
        #pragma unroll
        for (int tn = 0; tn < NTC; tn++) {
            const int r = wc * (NTC * 32) + tn * 32 + lrow;
            bf[tn] = *(const i32x4v*)(BsB + r * BK + ((slot ^ fswz(r)) * 16));
        }
    };

    auto mfma_slice = [&](i32x4v (&af)[MT], i32x4v (&bf)[NTC]) {
        #pragma unroll
        for (int tm = 0; tm < MT; tm++)
            #pragma unroll
            for (int tn = 0; tn < NTC; tn++)
                acc[tm][tn] = __builtin_amdgcn_mfma_i32_32x32x32_i8(
                    af[tm], bf[tn], acc[tm][tn], 0, 0, 0);
    };

    #define WAIT_CNT()  do { \
        if constexpr (WAITN == 2)      asm volatile("s_waitcnt vmcnt(2)" ::: "memory"); \
        else if constexpr (WAITN == 3) asm volatile("s_waitcnt vmcnt(3)" ::: "memory"); \
        else if constexpr (WAITN == 4) asm volatile("s_waitcnt vmcnt(4)" ::: "memory"); \
        else if constexpr (WAITN == 5) asm volatile("s_waitcnt vmcnt(5)" ::: "memory"); \
        else                           asm volatile("s_waitcnt vmcnt(6)" ::: "memory"); \
    } while (0)

    // prologue: tile 0 fully staged into buf 0
    #pragma unroll
    for (int j = 0; j < LOADS; j++) stage_one(0, 0, j);

    for (int t = 0; t < NT; t++) {
        const int cur = t & 1;
        const signed char* AsB = As[cur];
        const signed char* BsB = Bs[cur];
        const int kn = (t + 1) * BK;
        const bool pf = (t + 1 < NT);

        if constexpr (BK == 64) {
            // ---- single phase per K-tile ----
            if (pf) {
                #pragma unroll
                for (int j = 0; j < LOADS; j++) stage_one(cur ^ 1, kn, j);
                WAIT_CNT();
            } else {
                asm volatile("s_waitcnt vmcnt(0)" ::: "memory");
            }
            __builtin_amdgcn_sched_barrier(0);
            __builtin_amdgcn_s_barrier();
            __builtin_amdgcn_sched_barrier(0);
            {
                i32x4v a0[MT], b0[NTC], a1[MT], b1[NTC];
                read_slice(AsB, BsB, 0, a0, b0);
                read_slice(AsB, BsB, 1, a1, b1);
                __builtin_amdgcn_s_setprio(1);
                mfma_slice(a0, b0);
                mfma_slice(a1, b1);
                __builtin_amdgcn_s_setprio(0);
            }
            __builtin_amdgcn_sched_barrier(0);
            __builtin_amdgcn_s_barrier();
        } else {
            // ---- two phases per K-tile (verified r9 path) ----
            if (pf) {
                #pragma unroll
                for (int j = 0; j < LOADS / 2; j++) stage_one(cur ^ 1, kn, j);
                WAIT_CNT();
            } else {
                asm volatile("s_waitcnt vmcnt(0)" ::: "memory");
            }
            __builtin_amdgcn_sched_barrier(0);
            __builtin_amdgcn_s_barrier();
            __builtin_amdgcn_sched_barrier(0);
            {
                i32x4v a0[MT], b0[NTC], a1[MT], b1[NTC];
                read_slice(AsB, BsB, 0, a0, b0);
                read_slice(AsB, BsB, 1, a1, b1);
                __builtin_amdgcn_s_setprio(1);
                mfma_slice(a0, b0);
                mfma_slice(a1, b1);
                __builtin_amdgcn_s_setprio(0);
            }
            __builtin_amdgcn_sched_barrier(0);
            __builtin_amdgcn_s_barrier();
            {
                i32x4v a0[MT], b0[NTC], a1[MT], b1[NTC];
                read_slice(AsB, BsB, 2, a0, b0);
                read_slice(AsB, BsB, 3, a1, b1);
                if (pf) {
                    #pragma unroll
                    for (int j = LOADS / 2; j < LOADS; j++) stage_one(cur ^ 1, kn, j);
                }
                __builtin_amdgcn_sched_barrier(0);
                __builtin_amdgcn_s_barrier();
                __builtin_amdgcn_sched_barrier(0);
                __builtin_amdgcn_s_setprio(1);
                mfma_slice(a0, b0);
                mfma_slice(a1, b1);
                __builtin_amdgcn_s_setprio(0);
            }
            __builtin_amdgcn_sched_barrier(0);
            __builtin_amdgcn_s_barrier();
        }
    }
    #undef WAIT_CNT

    const float sw = *swp;
    #pragma unroll
    for (int tm = 0; tm < MT; tm++) {
        #pragma unroll
        for (int tn = 0; tn < NTC; tn++) {
            #pragma unroll
            for (int rg = 0; rg < 16; rg++) {
                const int rin  = (rg & 3) + 8 * (rg >> 2) + 4 * lhalf;
                const int grow = bm * BM + wr * (MT * 32) + tm * 32 + rin;
                const int gcol = bn * BN + wc * (NTC * 32) + tn * 32 + lrow;
                const float v = (float)acc[tm][tn][rg] * sa[grow] * sw;
                const size_t idx = (size_t)grow * Nn + gcol;
                if (EP == 0) {
                    float rv = fmaxf(v, 0.f);
                    out_bf[idx] = f2bf(rv * rv);
                } else if (EP == 1) {
                    out_f[idx] = 1.0f / (1.0f + expf(-v));
                } else {
                    out_f[idx] = gate[idx] * v;
                }
            }
        }
    }
}

extern "C" void kernel_launch(void* const* d_in, const int* in_sizes, int n_in,
                              void* d_out, int out_size, void* d_ws, size_t ws_size,
                              hipStream_t stream) {
    const float* x   = (const float*)d_in[0];
    const float* muk = (const float*)d_in[1];
    const float* mur = (const float*)d_in[2];
    const float* wk  = (const float*)d_in[3];
    const float* gk  = (const float*)d_in[4];
    const float* bk  = (const float*)d_in[5];
    const float* wr  = (const float*)d_in[6];
    const float* gr  = (const float*)d_in[7];
    const float* br  = (const float*)d_in[8];
    const float* wv  = (const float*)d_in[9];
    const float* gv  = (const float*)d_in[10];
    const float* bv  = (const float*)d_in[11];

    // ---- adaptive workspace layout (pure function of ws_size) ----
    char* wsb = (char*)d_ws;
    size_t off = 0;
    auto alloc = [&](size_t bytes) -> size_t {
        size_t p = off;
        off = (off + bytes + 255) & ~(size_t)255;
        return p;
    };
    const size_t o_wqk  = alloc((size_t)H_DIM * D_DIM);
    const size_t o_wqr  = alloc((size_t)D_DIM * D_DIM);
    const size_t o_wqv  = alloc((size_t)D_DIM * H_DIM);
    const size_t o_wsc  = alloc(64);
    const size_t o_part = alloc(3 * 1024 * sizeof(float));
    const size_t fixed  = off;

    // per-chunk: xqk(CH*D)+xqr(CH*D)+xqv(CH*H)+kact(CH*H*2 bf16)+gate(CH*D*4)+scales
    int CH = BT;
    while (CH > 512 &&
           fixed + (size_t)CH * (D_DIM + D_DIM + H_DIM + 2 * H_DIM + 4 * D_DIM + 12) + 8192 > ws_size)
        CH >>= 1;
    const size_t o_xqk  = alloc((size_t)CH * D_DIM);
    const size_t o_xqr  = alloc((size_t)CH * D_DIM);
    const size_t o_xqv  = alloc((size_t)CH * H_DIM);
    const size_t o_kact = alloc((size_t)CH * H_DIM * 2);
    const size_t o_gate = alloc((size_t)CH * D_DIM * 4);
    const size_t o_sk   = alloc((size_t)CH * 4);
    const size_t o_sr   = alloc((size_t)CH * 4);
    const size_t o_sv   = alloc((size_t)CH * 4);

    signed char* wqk = (signed char*)(wsb + o_wqk);
    signed char* wqr = (signed char*)(wsb + o_wqr);
    signed char* wqv = (signed char*)(wsb + o_wqv);
    float* wsc  = (float*)(wsb + o_wsc);
    float* part = (float*)(wsb + o_part);
    signed char* xqk = (signed char*)(wsb + o_xqk);
    signed char* xqr = (signed char*)(wsb + o_xqr);
    signed char* xqv = (signed char*)(wsb + o_xqv);
    unsigned short* kact = (unsigned short*)(wsb + o_kact);
    float* gate = (float*)(wsb + o_gate);
    float* sk = (float*)(wsb + o_sk);
    float* sr = (float*)(wsb + o_sr);
    float* sv = (float*)(wsb + o_sv);

    float* outp = (float*)d_out;                 // f32 output
    float* out2 = outp + (size_t)BT * D_DIM;     // f32 last-token passthrough

    // ---- weight scales + ternary quant ----
    wabs_partial<<<1024, 256, 0, stream>>>(wk, H_DIM * D_DIM, part + 0 * 1024);
    wabs_partial<<<1024, 256, 0, stream>>>(wr, D_DIM * D_DIM, part + 1 * 1024);
    wabs_partial<<<1024, 256, 0, stream>>>(wv, D_DIM * H_DIM, part + 2 * 1024);
    wfinal<<<1, 256, 0, stream>>>(part + 0 * 1024, 1024, H_DIM * D_DIM, wsc + 0);
    wfinal<<<1, 256, 0, stream>>>(part + 1 * 1024, 1024, D_DIM * D_DIM, wsc + 1);
    wfinal<<<1, 256, 0, stream>>>(part + 2 * 1024, 1024, D_DIM * H_DIM, wsc + 2);
    wquant<<<2048, 256, 0, stream>>>(wk, wsc + 0, wqk, H_DIM * D_DIM);
    wquant<<<2048, 256, 0, stream>>>(wr, wsc + 1, wqr, D_DIM * D_DIM);
    wquant<<<2048, 256, 0, stream>>>(wv, wsc + 2, wqv, D_DIM * H_DIM);

    // ---- row-chunked pipeline ----
    for (int row0 = 0; row0 < BT; row0 += CH) {
        act_prep<<<CH, 256, 0, stream>>>(x, row0, muk, gk, bk, mur, gr, br,
                                         xqk, sk, xqr, sr, out2);

        // gate = sigmoid(bitlinear_r)  (f32)   [256x128, BK=128, 4x2 waves]
        gemm8<1, 256, 128, 4, 2, 128><<<(CH / 256) * (D_DIM / 128), 512, 0, stream>>>(
            xqr, wqr, D_DIM, D_DIM, D_DIM / 128, sr, wsc + 1,
            (const float*)nullptr, gate, (unsigned short*)nullptr);

        // kact = relu(bitlinear_k)^2  (bf16)   [512x128, BK=64, 8x1 waves]
        gemm8<0, 512, 128, 8, 1, 64><<<(CH / 512) * (H_DIM / 128), 512, 0, stream>>>(
            xqk, wqk, D_DIM, H_DIM, H_DIM / 128, sk, wsc + 0,
            (const float*)nullptr, (float*)nullptr, kact);

        lnq_v<<<CH, 256, 0, stream>>>(kact, gv, bv, xqv, sv);

        // out = gate * bitlinear_v  (f32 -> d_out)   [256x128, BK=128, 4x2 waves]
        gemm8<2, 256, 128, 4, 2, 128><<<(CH / 256) * (D_DIM / 128), 512, 0, stream>>>(
            xqv, wqv, H_DIM, D_DIM, D_DIM / 128, sv, wsc + 2,
            gate, outp + (size_t)row0 * D_DIM, (unsigned short*)nullptr);
    }
}

// Round 11
// 652.654 us; speedup vs baseline: 1.1587x; 1.0608x over previous
//
#include <hip/hip_runtime.h>

// ---------------- problem constants ----------------
#define T_LEN 2048
#define B_SZ  4
#define D_DIM 2048
#define H_DIM 8192
#define BT    (B_SZ * T_LEN)

typedef float f32x4 __attribute__((ext_vector_type(4)));
typedef int   i32x4v __attribute__((ext_vector_type(4)));
typedef int   i32x16v __attribute__((ext_vector_type(16)));
typedef unsigned short ushort8 __attribute__((ext_vector_type(8)));

__device__ __forceinline__ float bf2f(unsigned short u) {
    unsigned int i = ((unsigned int)u) << 16;
    return __builtin_bit_cast(float, i);
}
__device__ __forceinline__ unsigned short f2bf(float f) {
    unsigned int i = __builtin_bit_cast(unsigned int, f);
    i += 0x7fffu + ((i >> 16) & 1u);   // RNE
    return (unsigned short)(i >> 16);
}

// ---------------- block reduction (blockDim == 256) ----------------
__device__ __forceinline__ float block_sum(float v, float* red) {
    #pragma unroll
    for (int o = 32; o > 0; o >>= 1) v += __shfl_down(v, o, 64);
    const int lane = threadIdx.x & 63, w = threadIdx.x >> 6;
    if (lane == 0) red[w] = v;
    __syncthreads();
    float r = red[0] + red[1] + red[2] + red[3];
    __syncthreads();
    return r;
}

// ---------------- fused weight-prep: abs-sum partials for all 3 matrices ----------------
__global__ void wabs_all(const float* __restrict__ wk, const float* __restrict__ wr,
                         const float* __restrict__ wv, float* __restrict__ part) {
    __shared__ float red[16];
    const int m = blockIdx.x >> 10;           // 0,1,2
    const int blk = blockIdx.x & 1023;
    const float* w = (m == 0) ? wk : (m == 1) ? wr : wv;
    const int n = (m == 1) ? D_DIM * D_DIM : H_DIM * D_DIM;
    float s = 0.f;
    int i = (blk * 256 + threadIdx.x) * 8;
    const int stride = 1024 * 256 * 8;
    for (; i < n; i += stride) {
        f32x4 a = *(const f32x4*)(w + i);
        f32x4 b = *(const f32x4*)(w + i + 4);
        #pragma unroll
        for (int j = 0; j < 4; j++) s += fabsf(a[j]) + fabsf(b[j]);
    }
    float tot = block_sum(s, red);
    if (threadIdx.x == 0) part[blockIdx.x] = tot;
}

__global__ void wfinal_all(const float* __restrict__ part, float* __restrict__ wsc) {
    __shared__ float red[16];
    const int m = blockIdx.x;
    const int n = (m == 1) ? D_DIM * D_DIM : H_DIM * D_DIM;
    float s = 0.f;
    for (int i = threadIdx.x; i < 1024; i += 256) s += part[m * 1024 + i];
    float tot = block_sum(s, red);
    if (threadIdx.x == 0) wsc[m] = fmaxf(tot / (float)n, 1e-8f);
}

__global__ void wquant_all(const float* __restrict__ wk, const float* __restrict__ wr,
                           const float* __restrict__ wv,
                           signed char* __restrict__ qk, signed char* __restrict__ qr,
                           signed char* __restrict__ qv,
                           const float* __restrict__ wsc) {
    const int b = blockIdx.x;
    int m, blk, nblk;
    if (b < 2048)      { m = 0; blk = b;        nblk = 2048; }
    else if (b < 3072) { m = 1; blk = b - 2048; nblk = 1024; }
    else               { m = 2; blk = b - 3072; nblk = 2048; }
    const float* w = (m == 0) ? wk : (m == 1) ? wr : wv;
    signed char* q = (m == 0) ? qk : (m == 1) ? qr : qv;
    const int n = (m == 1) ? D_DIM * D_DIM : H_DIM * D_DIM;
    const float s = wsc[m];
    int i = (blk * 256 + threadIdx.x) * 16;
    const int stride = nblk * 256 * 16;
    for (; i < n; i += stride) {
        union { signed char c[16]; i32x4v v; } pk;
        #pragma unroll
        for (int h = 0; h < 4; h++) {
            f32x4 a = *(const f32x4*)(w + i + h * 4);
            #pragma unroll
            for (int j = 0; j < 4; j++)
                pk.c[h * 4 + j] =
                    (signed char)(int)rintf(fminf(fmaxf(a[j] / s, -1.f), 1.f));
        }
        *(i32x4v*)(q + i) = pk.v;
    }
}

// ---------------- LN + act quant (8 elems/thread, D=2048) ----------------
__device__ __forceinline__ void ln_quant8(const float* xm_in,
                                          const float* __restrict__ g,
                                          const float* __restrict__ b,
                                          signed char* qrow, float* srow, float* red) {
    const int base = threadIdx.x * 8;
    float xm[8];
    float s = 0.f;
    #pragma unroll
    for (int j = 0; j < 8; j++) { xm[j] = xm_in[j]; s += xm[j]; }
    const float mean = block_sum(s, red) * (1.f / D_DIM);
    float s2 = 0.f;
    #pragma unroll
    for (int j = 0; j < 8; j++) { float d = xm[j] - mean; s2 += d * d; }
    const float var  = block_sum(s2, red) * (1.f / D_DIM);
    const float rstd = 1.f / sqrtf(var + 1e-5f);
    f32x4 ga = *(const f32x4*)(g + base), gb = *(const f32x4*)(g + base + 4);
    f32x4 ba = *(const f32x4*)(b + base), bb2 = *(const f32x4*)(b + base + 4);
    float gg[8] = {ga[0],ga[1],ga[2],ga[3],gb[0],gb[1],gb[2],gb[3]};
    float bb[8] = {ba[0],ba[1],ba[2],ba[3],bb2[0],bb2[1],bb2[2],bb2[3]};
    float sa = 0.f;
    #pragma unroll
    for (int j = 0; j < 8; j++) {
        xm[j] = (xm[j] - mean) * rstd * gg[j] + bb[j];
        sa += fabsf(xm[j]);
    }
    const float amean = block_sum(sa, red) * (1.f / D_DIM);
    const float scale = fmaxf(amean, 1e-8f) * 2.5f / 127.0f;
    union { signed char c[8]; int2 v; } pk;
    #pragma unroll
    for (int j = 0; j < 8; j++)
        pk.c[j] = (signed char)(int)rintf(fminf(fmaxf(xm[j] / scale, -127.f), 127.f));
    *(int2*)(qrow + base) = pk.v;
    if (threadIdx.x == 0) *srow = scale;
}

// ------- token shift + both LN/quant paths + out2 passthrough (f32), full BT -------
__global__ void act_prep(const float* __restrict__ x,
                         const float* __restrict__ muk,
                         const float* __restrict__ gk, const float* __restrict__ bk,
                         const float* __restrict__ mur,
                         const float* __restrict__ gr, const float* __restrict__ br,
                         signed char* __restrict__ qk, float* __restrict__ sk,
                         signed char* __restrict__ qr, float* __restrict__ sr,
                         float* __restrict__ out2) {
    __shared__ float red[16];
    const int row = blockIdx.x;
    const int t = row & (T_LEN - 1);
    const int base = threadIdx.x * 8;

    float xv[8], xp[8];
    f32x4 xa = *(const f32x4*)(x + (size_t)row * D_DIM + base);
    f32x4 xb = *(const f32x4*)(x + (size_t)row * D_DIM + base + 4);
    xv[0]=xa[0]; xv[1]=xa[1]; xv[2]=xa[2]; xv[3]=xa[3];
    xv[4]=xb[0]; xv[5]=xb[1]; xv[6]=xb[2]; xv[7]=xb[3];
    if (t > 0) {
        f32x4 pa = *(const f32x4*)(x + (size_t)(row - 1) * D_DIM + base);
        f32x4 pb = *(const f32x4*)(x + (size_t)(row - 1) * D_DIM + base + 4);
        xp[0]=pa[0]; xp[1]=pa[1]; xp[2]=pa[2]; xp[3]=pa[3];
        xp[4]=pb[0]; xp[5]=pb[1]; xp[6]=pb[2]; xp[7]=pb[3];
    } else {
        #pragma unroll
        for (int j = 0; j < 8; j++) xp[j] = 0.f;
    }
    if (t == T_LEN - 1) {
        const int bb = row / T_LEN;
        *(f32x4*)(out2 + (size_t)bb * D_DIM + base)     = xa;   // f32 x[:, -1, :]
        *(f32x4*)(out2 + (size_t)bb * D_DIM + base + 4) = xb;
    }
    float mk[8], mr[8], xmk[8], xmr[8];
    f32x4 mka = *(const f32x4*)(muk + base), mkb = *(const f32x4*)(muk + base + 4);
    f32x4 mra = *(const f32x4*)(mur + base), mrb = *(const f32x4*)(mur + base + 4);
    mk[0]=mka[0]; mk[1]=mka[1]; mk[2]=mka[2]; mk[3]=mka[3];
    mk[4]=mkb[0]; mk[5]=mkb[1]; mk[6]=mkb[2]; mk[7]=mkb[3];
    mr[0]=mra[0]; mr[1]=mra[1]; mr[2]=mra[2]; mr[3]=mra[3];
    mr[4]=mrb[0]; mr[5]=mrb[1]; mr[6]=mrb[2]; mr[7]=mrb[3];
    #pragma unroll
    for (int j = 0; j < 8; j++) {
        const float dx = xp[j] - xv[j];
        xmk[j] = xv[j] + dx * mk[j];
        xmr[j] = xv[j] + dx * mr[j];
    }
    ln_quant8(xmk, gk, bk, qk + (size_t)row * D_DIM, sk + row, red);
    ln_quant8(xmr, gr, br, qr + (size_t)row * D_DIM, sr + row, red);
}

// -------- LN + act quant over H=8192 (k_act bf16 rows) --------
__global__ void lnq_v(const unsigned short* __restrict__ kact,
                      const float* __restrict__ g, const float* __restrict__ b,
                      signed char* __restrict__ qv, float* __restrict__ sv) {
    __shared__ float red[16];
    const int row = blockIdx.x;
    const int base = threadIdx.x * 32;
    const unsigned short* kr = kact + (size_t)row * H_DIM + base;

    float v[32];
    float s = 0.f;
    #pragma unroll
    for (int c = 0; c < 4; c++) {
        ushort8 a = *(const ushort8*)(kr + c * 8);
        #pragma unroll
        for (int j = 0; j < 8; j++) { v[c * 8 + j] = bf2f(a[j]); s += v[c * 8 + j]; }
    }
    const float mean = block_sum(s, red) * (1.f / H_DIM);
    float s2 = 0.f;
    #pragma unroll
    for (int j = 0; j < 32; j++) { float d = v[j] - mean; s2 += d * d; }
    const float var  = block_sum(s2, red) * (1.f / H_DIM);
    const float rstd = 1.f / sqrtf(var + 1e-5f);
    float sa = 0.f;
    #pragma unroll
    for (int c = 0; c < 8; c++) {
        f32x4 ga = *(const f32x4*)(g + base + c * 4);
        f32x4 ba = *(const f32x4*)(b + base + c * 4);
        #pragma unroll
        for (int j = 0; j < 4; j++) {
            int k = c * 4 + j;
            v[k] = (v[k] - mean) * rstd * ga[j] + ba[j];
            sa += fabsf(v[k]);
        }
    }
    const float amean = block_sum(sa, red) * (1.f / H_DIM);
    const float scale = fmaxf(amean, 1e-8f) * 2.5f / 127.0f;
    union { signed char c[32]; i32x4v v4[2]; } pk;
    #pragma unroll
    for (int j = 0; j < 32; j++)
        pk.c[j] = (signed char)(int)rintf(fminf(fmaxf(v[j] / scale, -127.f), 127.f));
    *(i32x4v*)(qv + (size_t)row * H_DIM + base)      = pk.v4[0];
    *(i32x4v*)(qv + (size_t)row * H_DIM + base + 16) = pk.v4[1];
    if (threadIdx.x == 0) sv[row] = scale;
}

// ======== gemmA: kact GEMM with A-in-registers (8x1 waves -> A has no cross-wave reuse)
// 512x128 tile, BK=64, 512 threads. B double-buffered in LDS (r10-verified BK=64 swizzle
// f(r)=(r>>1)&3: linear gload_lds dest + inverse-swz global src + swz ds_read).
// A fragments loaded per-lane direct from global (identical bytes: XOR cancels).
// 2-K-tile unrolled loop, named a0/a1 reg sets, counted vmcnt(5) (1 B-stage + 4 A-loads).
// Epilogue: relu(v)^2 -> bf16.
__global__ __launch_bounds__(512, 2) void gemmA(
    const signed char* __restrict__ A, const signed char* __restrict__ B,
    int K, int Nn, int gn,
    const float* __restrict__ sa, const float* __restrict__ swp,
    unsigned short* __restrict__ out_bf) {
    __shared__ signed char Bs[2][128 * 64];
    const int tid = threadIdx.x;
    const int nwg = gridDim.x, q8 = nwg >> 3;
    const int swz = (blockIdx.x & 7) * q8 + (blockIdx.x >> 3);
    const int bm = swz / gn, bn = swz % gn;
    const int lane = tid & 63, wave = tid >> 6;
    const int lrow = lane & 31, lhalf = lane >> 5;
    const size_t arow0 = (size_t)bm * 512;
    const size_t brow0 = (size_t)bn * 128;
    const int NT = K >> 6;   // 32 (even)

    i32x16v acc[2][4] = {};

    auto stageB = [&](int buf, int k0) {
        const int r = tid >> 2, sl = tid & 3;
        const signed char* g = B + (brow0 + r) * (size_t)K + k0 + ((sl ^ ((r >> 1) & 3)) * 16);
        __builtin_amdgcn_global_load_lds(
            (const __attribute__((address_space(1))) void*)g,
            (__attribute__((address_space(3))) void*)(Bs[buf] + tid * 16), 16, 0, 0);
    };
    auto loadA = [&](i32x4v (&a)[2][2], int k0) {
        #pragma unroll
        for (int tm = 0; tm < 2; tm++)
            #pragma unroll
            for (int s = 0; s < 2; s++) {
                const int r = wave * 64 + tm * 32 + lrow;
                a[tm][s] = *(const i32x4v*)(A + (arow0 + r) * (size_t)K + k0 + (s * 2 + lhalf) * 16);
            }
    };
    auto readB = [&](const signed char* BsB, i32x4v (&b)[4][2]) {
        #pragma unroll
        for (int s = 0; s < 2; s++) {
            const int slot = s * 2 + lhalf;
            #pragma unroll
            for (int tn = 0; tn < 4; tn++) {
                const int r = tn * 32 + lrow;
                b[tn][s] = *(const i32x4v*)(BsB + r * 64 + ((slot ^ ((r >> 1) & 3)) * 16));
            }
        }
    };
    auto mfma8 = [&](i32x4v (&a)[2][2], i32x4v (&b)[4][2]) {
        #pragma unroll
        for (int s = 0; s < 2; s++)
            #pragma unroll
            for (int tm = 0; tm < 2; tm++)
                #pragma unroll
                for (int tn = 0; tn < 4; tn++)
                    acc[tm][tn] = __builtin_amdgcn_mfma_i32_32x32x32_i8(
                        a[tm][s], b[tn][s], acc[tm][tn], 0, 0, 0);
    };

    i32x4v a0[2][2], a1[2][2];
    stageB(0, 0);
    loadA(a0, 0);
    for (int it = 0; it < NT / 2; it++) {
        const int t0 = 2 * it, t1 = t0 + 1;
        // ---- tile t0: buf 0, regs a0 ----
        stageB(1, t1 << 6);
        loadA(a1, t1 << 6);
        asm volatile("s_waitcnt vmcnt(5)" ::: "memory");   // prev 5 done: Bs[0] + a0 ready
        __builtin_amdgcn_sched_barrier(0);
        __builtin_amdgcn_s_barrier();
        __builtin_amdgcn_sched_barrier(0);
        {
            i32x4v b[4][2];
            readB(Bs[0], b);
            __builtin_amdgcn_s_setprio(1);
            mfma8(a0, b);
            __builtin_amdgcn_s_setprio(0);
        }
        __builtin_amdgcn_sched_barrier(0);
        __builtin_amdgcn_s_barrier();      // all waves done reading Bs[0]
        // ---- tile t1: buf 1, regs a1 ----
        if (t1 + 1 < NT) {
            stageB(0, (t1 + 1) << 6);
            loadA(a0, (t1 + 1) << 6);
            asm volatile("s_waitcnt vmcnt(5)" ::: "memory");
        } else {
            asm volatile("s_waitcnt vmcnt(0)" ::: "memory");
        }
        __builtin_amdgcn_sched_barrier(0);
        __builtin_amdgcn_s_barrier();
        __builtin_amdgcn_sched_barrier(0);
        {
            i32x4v b[4][2];
            readB(Bs[1], b);
            __builtin_amdgcn_s_setprio(1);
            mfma8(a1, b);
            __builtin_amdgcn_s_setprio(0);
        }
        __builtin_amdgcn_sched_barrier(0);
        __builtin_amdgcn_s_barrier();
    }

    const float sw = *swp;
    #pragma unroll
    for (int tm = 0; tm < 2; tm++) {
        #pragma unroll
        for (int tn = 0; tn < 4; tn++) {
            #pragma unroll
            for (int rg = 0; rg < 16; rg++) {
                const int rin  = (rg & 3) + 8 * (rg >> 2) + 4 * lhalf;
                const int grow = bm * 512 + wave * 64 + tm * 32 + rin;
                const int gcol = bn * 128 + tn * 32 + lrow;
                const float v = (float)acc[tm][tn][rg] * sa[grow] * sw;
                float rv = fmaxf(v, 0.f);
                out_bf[(size_t)grow * Nn + gcol] = f2bf(rv * rv);
            }
        }
    }
}

// ======== gemm_i8: r6-verified 256-thread 128x128 tile, 4 waves (2x2), BK=128 ========
// EP: 1 = sigmoid(v) -> bf16 gate;  2 = out_f32 = bf16(gate) * v.
template <int EP>
__global__ __launch_bounds__(256) void gemm_i8(
    const signed char* __restrict__ A, const signed char* __restrict__ B,
    int K, int Nn,
    const float* __restrict__ sa, const float* __restrict__ swp,
    const unsigned short* __restrict__ gate_bf, float* __restrict__ out_f,
    unsigned short* __restrict__ out_gbf) {
    __shared__ signed char As[128 * 128];
    __shared__ signed char Bs[128 * 128];
    const int tid  = threadIdx.x;
    const int bm   = blockIdx.x, bn = blockIdx.y;
    const int lane = tid & 63, wave = tid >> 6;
    const int wr = wave >> 1, wc = wave & 1;
    const int lrow = lane & 31, lhalf = lane >> 5;

    i32x16v acc[2][2] = {};

    int srow[4], scol[4];
    #pragma unroll
    for (int i = 0; i < 4; i++) {
        int o = i * 256 + tid;
        int r = o >> 3, sl = o & 7;
        srow[i] = r;
        scol[i] = ((sl ^ (r & 7)) * 16);
    }
    const size_t arow0 = (size_t)bm * 128;
    const size_t brow0 = (size_t)bn * 128;

    for (int k0 = 0; k0 < K; k0 += 128) {
        __syncthreads();
        #pragma unroll
        for (int i = 0; i < 4; i++) {
            const signed char* ga = A + (arow0 + srow[i]) * (size_t)K + k0 + scol[i];
            const signed char* gb = B + (brow0 + srow[i]) * (size_t)K + k0 + scol[i];
            __builtin_amdgcn_global_load_lds(
                (const __attribute__((address_space(1))) void*)ga,
                (__attribute__((address_space(3))) void*)(As + (i * 256 + tid) * 16),
                16, 0, 0);
            __builtin_amdgcn_global_load_lds(
                (const __attribute__((address_space(1))) void*)gb,
                (__attribute__((address_space(3))) void*)(Bs + (i * 256 + tid) * 16),
                16, 0, 0);
        }
        __syncthreads();

        #pragma unroll
        for (int ks = 0; ks < 4; ks++) {
            const int slot = ks * 2 + lhalf;
            i32x4v af[2], bfv[2];
            #pragma unroll
            for (int tm = 0; tm < 2; tm++) {
                int r = wr * 64 + tm * 32 + lrow;
                af[tm] = *(const i32x4v*)(As + r * 128 + ((slot ^ (r & 7)) * 16));
            }
            #pragma unroll
            for (int tn = 0; tn < 2; tn++) {
                int r = wc * 64 + tn * 32 + lrow;
                bfv[tn] = *(const i32x4v*)(Bs + r * 128 + ((slot ^ (r & 7)) * 16));
            }
            #pragma unroll
            for (int tm = 0; tm < 2; tm++)
                #pragma unroll
                for (int tn = 0; tn < 2; tn++)
                    acc[tm][tn] = __builtin_amdgcn_mfma_i32_32x32x32_i8(
                        af[tm], bfv[tn], acc[tm][tn], 0, 0, 0);
        }
    }

    const float sw = *swp;
    #pragma unroll
    for (int tm = 0; tm < 2; tm++) {
        #pragma unroll
        for (int tn = 0; tn < 2; tn++) {
            #pragma unroll
            for (int rg = 0; rg < 16; rg++) {
                const int rin  = (rg & 3) + 8 * (rg >> 2) + 4 * lhalf;
                const int grow = bm * 128 + wr * 64 + tm * 32 + rin;
                const int gcol = bn * 128 + wc * 64 + tn * 32 + lrow;
                const float v = (float)acc[tm][tn][rg] * sa[grow] * sw;
                const size_t idx = (size_t)grow * Nn + gcol;
                if (EP == 1) {
                    out_gbf[idx] = f2bf(1.0f / (1.0f + expf(-v)));
                } else {
                    out_f[idx] = bf2f(gate_bf[idx]) * v;
                }
            }
        }
    }
}

extern "C" void kernel_launch(void* const* d_in, const int* in_sizes, int n_in,
                              void* d_out, int out_size, void* d_ws, size_t ws_size,
                              hipStream_t stream) {
    const float* x   = (const float*)d_in[0];
    const float* muk = (const float*)d_in[1];
    const float* mur = (const float*)d_in[2];
    const float* wk  = (const float*)d_in[3];
    const float* gk  = (const float*)d_in[4];
    const float* bk  = (const float*)d_in[5];
    const float* wr  = (const float*)d_in[6];
    const float* gr  = (const float*)d_in[7];
    const float* br  = (const float*)d_in[8];
    const float* wv  = (const float*)d_in[9];
    const float* gv  = (const float*)d_in[10];
    const float* bv  = (const float*)d_in[11];

    // ---- adaptive workspace layout (pure function of ws_size) ----
    char* wsb = (char*)d_ws;
    size_t off = 0;
    auto alloc = [&](size_t bytes) -> size_t {
        size_t p = off;
        off = (off + bytes + 255) & ~(size_t)255;
        return p;
    };
    const size_t o_wqk  = alloc((size_t)H_DIM * D_DIM);
    const size_t o_wqr  = alloc((size_t)D_DIM * D_DIM);
    const size_t o_wqv  = alloc((size_t)D_DIM * H_DIM);
    const size_t o_wsc  = alloc(64);
    const size_t o_part = alloc(3 * 1024 * sizeof(float));
    const size_t o_xqk  = alloc((size_t)BT * D_DIM);        // full
    const size_t o_xqr  = alloc((size_t)BT * D_DIM);        // full
    const size_t o_gate = alloc((size_t)BT * D_DIM * 2);    // full, bf16
    const size_t o_sk   = alloc((size_t)BT * 4);
    const size_t o_sr   = alloc((size_t)BT * 4);
    const size_t fixed  = off;

    // per-chunk: xqv(CH*H) + kact(CH*H*2) + sv(CH*4)
    int CH = BT;
    while (CH > 512 &&
           fixed + (size_t)CH * (H_DIM + 2 * H_DIM + 4) + 8192 > ws_size)
        CH >>= 1;
    const size_t o_xqv  = alloc((size_t)CH * H_DIM);
    const size_t o_kact = alloc((size_t)CH * H_DIM * 2);
    const size_t o_sv   = alloc((size_t)CH * 4);

    signed char* wqk = (signed char*)(wsb + o_wqk);
    signed char* wqr = (signed char*)(wsb + o_wqr);
    signed char* wqv = (signed char*)(wsb + o_wqv);
    float* wsc  = (float*)(wsb + o_wsc);
    float* part = (float*)(wsb + o_part);
    signed char* xqk = (signed char*)(wsb + o_xqk);
    signed char* xqr = (signed char*)(wsb + o_xqr);
    unsigned short* gate = (unsigned short*)(wsb + o_gate);
    float* sk = (float*)(wsb + o_sk);
    float* sr = (float*)(wsb + o_sr);
    signed char* xqv = (signed char*)(wsb + o_xqv);
    unsigned short* kact = (unsigned short*)(wsb + o_kact);
    float* sv = (float*)(wsb + o_sv);

    float* outp = (float*)d_out;                 // f32 output
    float* out2 = outp + (size_t)BT * D_DIM;     // f32 last-token passthrough

    // ---- fused weight prep (3 launches) ----
    wabs_all<<<3072, 256, 0, stream>>>(wk, wr, wv, part);
    wfinal_all<<<3, 256, 0, stream>>>(part, wsc);
    wquant_all<<<5120, 256, 0, stream>>>(wk, wr, wv, wqk, wqr, wqv, wsc);

    // ---- token shift + LN + act quant, full BT ----
    act_prep<<<BT, 256, 0, stream>>>(x, muk, gk, bk, mur, gr, br,
                                     xqk, sk, xqr, sr, out2);

    // gate = sigmoid(bitlinear_r) -> bf16, full BT
    gemm_i8<1><<<dim3(BT / 128, D_DIM / 128), 256, 0, stream>>>(
        xqr, wqr, D_DIM, D_DIM, sr, wsc + 1,
        (const unsigned short*)nullptr, (float*)nullptr, gate);

    // ---- row-chunked: kact -> lnq_v -> out ----
    for (int row0 = 0; row0 < BT; row0 += CH) {
        // kact = relu(bitlinear_k)^2 -> bf16   [A-in-reg gemm, 512x128, BK=64]
        gemmA<<<(CH / 512) * (H_DIM / 128), 512, 0, stream>>>(
            xqk + (size_t)row0 * D_DIM, wqk, D_DIM, H_DIM, H_DIM / 128,
            sk + row0, wsc + 0, kact);

        lnq_v<<<CH, 256, 0, stream>>>(kact, gv, bv, xqv, sv);

        // out = bf16(gate) * bitlinear_v  (f32 -> d_out)
        gemm_i8<2><<<dim3(CH / 128, D_DIM / 128), 256, 0, stream>>>(
            xqv, wqv, H_DIM, D_DIM, sv, wsc + 2,
            gate + (size_t)row0 * D_DIM, outp + (size_t)row0 * D_DIM,
            (unsigned short*)nullptr);
    }
}